// Round 1
// baseline (1104.136 us; speedup 1.0000x reference)
//
#include <hip/hip_runtime.h>
#include <math.h>

#define N 1024
#define BLK 256

__device__ __forceinline__ unsigned long long pack_key(float v, int idx) {
    // distances are >= 0 (or +INF), so float bit pattern preserves order as uint
    return ((unsigned long long)__float_as_uint(v) << 32) | (unsigned)idx;
}

// One block per (input, batch): blk in [0,128); blk<64 -> gts, else preds.
__global__ __launch_bounds__(BLK) void prim_kernel(const float* __restrict__ gts,
                                                   const float* __restrict__ preds,
                                                   float* __restrict__ ws) {
    __shared__ float px[N], py[N], pz[N], sq[N];
    __shared__ float md[N];       // min_dist; +INF marks "in tree"
    __shared__ float deaths[N];   // 1023 deaths + 1 pad
    __shared__ unsigned long long wred[4];

    const int t = threadIdx.x;
    const int blk = blockIdx.x;
    const int b = blk & 63;
    const float* src = (blk < 64 ? gts : preds) + (size_t)b * N * 3;

    // stage points into LDS (SoA)
    for (int e = t; e < N * 3; e += BLK) {
        float v = src[e];
        int k = e / 3, c = e - k * 3;
        if (c == 0) px[k] = v; else if (c == 1) py[k] = v; else pz[k] = v;
    }
    __syncthreads();
    for (int k = t; k < N; k += BLK)
        sq[k] = px[k] * px[k] + py[k] * py[k] + pz[k] * pz[k];
    __syncthreads();

    // init: node 0 in tree, min_dist = D[0][:]
    {
        float x0 = px[0], y0 = py[0], z0 = pz[0], s0 = sq[0];
        for (int k = t; k < N; k += BLK) {
            float dot = px[k] * x0 + py[k] * y0 + pz[k] * z0;
            float d2 = s0 + sq[k] - 2.0f * dot;
            float d = sqrtf(fmaxf(d2, 0.0f) + 1e-12f);
            md[k] = (k == 0) ? INFINITY : d;
        }
    }
    __syncthreads();

    const int lane = t & 63;
    const int wid = t >> 6;

    for (int it = 0; it < N - 1; ++it) {
        // ---- argmin over md (in-tree entries are +INF) ----
        unsigned long long key = 0xFFFFFFFFFFFFFFFFull;
        #pragma unroll
        for (int q = 0; q < N / BLK; ++q) {
            int k = t + q * BLK;
            unsigned long long kk = pack_key(md[k], k);
            key = kk < key ? kk : key;
        }
        #pragma unroll
        for (int off = 32; off > 0; off >>= 1) {
            unsigned long long o = __shfl_xor(key, off, 64);
            key = o < key ? o : key;
        }
        if (lane == 0) wred[wid] = key;
        __syncthreads();
        {
            unsigned long long k0 = wred[0], k1 = wred[1], k2 = wred[2], k3 = wred[3];
            k0 = k1 < k0 ? k1 : k0;
            k2 = k3 < k2 ? k3 : k2;
            key = k2 < k0 ? k2 : k0;
        }
        int j = (int)(key & 0xFFFFFFFFu);
        float death = __uint_as_float((unsigned)(key >> 32));
        if (t == 0) deaths[it] = death;

        // ---- relax against new node j ----
        float xj = px[j], yj = py[j], zj = pz[j], sj = sq[j];
        #pragma unroll
        for (int q = 0; q < N / BLK; ++q) {
            int k = t + q * BLK;
            float old = md[k];
            float dot = px[k] * xj + py[k] * yj + pz[k] * zj;
            float d2 = sj + sq[k] - 2.0f * dot;
            float d = sqrtf(fmaxf(d2, 0.0f) + 1e-12f);
            bool intree = (old == INFINITY) || (k == j);
            md[k] = intree ? INFINITY : fminf(old, d);
        }
        __syncthreads();  // protects wred rewrite next iteration + md visibility
    }

    // ---- bitonic sort deaths[0..1023] ascending (pad with +INF) ----
    if (t == 0) deaths[N - 1] = INFINITY;
    __syncthreads();
    for (int k = 2; k <= N; k <<= 1) {
        for (int j = k >> 1; j > 0; j >>= 1) {
            for (int i = t; i < N; i += BLK) {
                int ixj = i ^ j;
                if (ixj > i) {
                    float a = deaths[i], c = deaths[ixj];
                    bool up = ((i & k) == 0);
                    if ((a > c) == up) { deaths[i] = c; deaths[ixj] = a; }
                }
            }
            __syncthreads();
        }
    }

    // write sorted deaths; pad slot becomes 0 so the diff kernel can sum 1024-wide
    float* dst = ws + (size_t)blk * N;
    for (int i = t; i < N; i += BLK)
        dst[i] = (i < N - 1) ? deaths[i] : 0.0f;
}

__global__ __launch_bounds__(256) void diff_kernel(const float* __restrict__ ws,
                                                   float* __restrict__ out) {
    __shared__ float red[256];
    const int t = threadIdx.x;
    float sum = 0.0f;
    for (int idx = t; idx < 64 * N; idx += 256)
        sum += fabsf(ws[idx] - ws[64 * N + idx]);
    red[t] = sum;
    __syncthreads();
    for (int s = 128; s > 0; s >>= 1) {
        if (t < s) red[t] += red[t + s];
        __syncthreads();
    }
    if (t == 0) out[0] = red[0] * (1.0f / 64.0f);
}

extern "C" void kernel_launch(void* const* d_in, const int* in_sizes, int n_in,
                              void* d_out, int out_size, void* d_ws, size_t ws_size,
                              hipStream_t stream) {
    const float* gts = (const float*)d_in[0];
    const float* preds = (const float*)d_in[1];
    float* ws = (float*)d_ws;  // needs 2*64*1024*4 = 512 KiB
    hipLaunchKernelGGL(prim_kernel, dim3(128), dim3(BLK), 0, stream, gts, preds, ws);
    hipLaunchKernelGGL(diff_kernel, dim3(1), dim3(256), 0, stream, ws, (float*)d_out);
}

// Round 2
// 765.005 us; speedup vs baseline: 1.4433x; 1.4433x over previous
//
#include <hip/hip_runtime.h>
#include <math.h>

#define N 1024
#define WAVE 64
#define QS 16   // slots per lane: N / WAVE

__device__ __forceinline__ unsigned umin32(unsigned a, unsigned b) { return a < b ? a : b; }

// DPP-based wave64 min-reduce step: v = min(v, dpp_shifted(v)), identity = 0xFFFFFFFF
#define DPP_MIN(v, ctrl, rmask)                                                              \
    do {                                                                                     \
        unsigned _t = (unsigned)__builtin_amdgcn_update_dpp(                                 \
            (int)0xFFFFFFFF, (int)(v), (ctrl), (rmask), 0xF, false);                         \
        (v) = umin32((v), _t);                                                               \
    } while (0)

// One wave per (input, batch). blk<64 -> gts, else preds.
__global__ __launch_bounds__(WAVE) void prim_kernel(const float* __restrict__ gts,
                                                    const float* __restrict__ preds,
                                                    float* __restrict__ ws) {
    __shared__ float4 pts[N];       // x, y, z, h = 0.5*|p|^2
    __shared__ unsigned keys[N];    // death keys (sortable uint = fp32 bits of e>=0)

    const int lane = threadIdx.x;
    const int blk = blockIdx.x;
    const int b = blk & 63;
    const float* __restrict__ src = (blk < 64 ? gts : preds) + (size_t)b * N * 3;

    // ---- stage points into LDS ----
    for (int k = lane; k < N; k += WAVE) {
        float x = src[3 * k], y = src[3 * k + 1], z = src[3 * k + 2];
        float h = 0.5f * (x * x + y * y + z * z);
        pts[k] = make_float4(x, y, z, h);
    }
    __syncthreads();

    // ---- register copies: slot q of this lane owns point k = q*64 + lane ----
    float px[QS], py[QS], pz[QS], ph[QS];
    unsigned md[QS];   // min "half-squared-distance" key; 0xFFFFFFFF / ~INF-bits = in tree
    #pragma unroll
    for (int q = 0; q < QS; ++q) {
        float4 p = pts[q * WAVE + lane];
        px[q] = p.x; py[q] = p.y; pz[q] = p.z; ph[q] = p.w;
    }

    // ---- init: node 0 in tree, md = e(k, 0) ----
    {
        float4 p0 = pts[0];
        #pragma unroll
        for (int q = 0; q < QS; ++q) {
            float e = ph[q] + p0.w - (px[q] * p0.x + py[q] * p0.y + pz[q] * p0.z);
            e = fmaxf(e, 0.0f);
            unsigned key = (__float_as_uint(e) & 0xFFFFFFF0u) | (unsigned)q;
            bool is0 = (q == 0) && (lane == 0);
            md[q] = is0 ? 0xFFFFFFFFu : key;
            ph[q] = is0 ? INFINITY : ph[q];   // poison: future e(k,*) = +INF
        }
    }

    // ---- Prim main loop: N-1 serial iterations ----
    for (int it = 0; it < N - 1; ++it) {
        // local min over 16 register slots
        unsigned lmin = md[0];
        #pragma unroll
        for (int q = 1; q < QS; ++q) lmin = umin32(lmin, md[q]);

        // wave min via DPP (result in lane 63)
        unsigned v = lmin;
        DPP_MIN(v, 0x111, 0xF);  // row_shr:1
        DPP_MIN(v, 0x112, 0xF);  // row_shr:2
        DPP_MIN(v, 0x114, 0xF);  // row_shr:4
        DPP_MIN(v, 0x118, 0xF);  // row_shr:8
        DPP_MIN(v, 0x142, 0xA);  // row_bcast:15 -> rows 1,3
        DPP_MIN(v, 0x143, 0xC);  // row_bcast:31 -> rows 2,3
        unsigned gmin = (unsigned)__builtin_amdgcn_readlane((int)v, 63);

        // winning lane + slot
        unsigned long long mask = __ballot(lmin == gmin);
        int w = __ffsll(mask) - 1;
        int qwin = (int)(gmin & 15u);
        int j = qwin * WAVE + w;

        if (lane == 0) keys[it] = gmin;

        // relax all owned slots against new node j
        float4 pj = pts[j];   // broadcast ds_read_b128
        bool amw = (lane == w);
        #pragma unroll
        for (int q = 0; q < QS; ++q) {
            bool isj = amw && (q == qwin);
            float e = ph[q] + pj.w - (px[q] * pj.x + py[q] * pj.y + pz[q] * pj.z);
            e = fmaxf(e, 0.0f);
            unsigned key = (__float_as_uint(e) & 0xFFFFFFF0u) | (unsigned)q;
            unsigned nm = umin32(md[q], key);
            md[q] = isj ? 0xFFFFFFFFu : nm;
            ph[q] = isj ? INFINITY : ph[q];
        }
    }

    if (lane == 0) keys[N - 1] = 0xFFFFFFFFu;   // pad: sorts to the end
    __syncthreads();

    // ---- bitonic sort of 1024 uint keys (ascending) ----
    for (int k = 2; k <= N; k <<= 1) {
        for (int j = k >> 1; j > 0; j >>= 1) {
            for (int base = 0; base < N; base += WAVE) {
                int i = base + lane;
                int ixj = i ^ j;
                if (ixj > i) {
                    unsigned a = keys[i], c = keys[ixj];
                    bool up = ((i & k) == 0);
                    if ((a > c) == up) { keys[i] = c; keys[ixj] = a; }
                }
            }
            __syncthreads();
        }
    }

    // ---- convert keys -> deaths, write sorted; pad slot -> 0 ----
    float* dst = ws + (size_t)blk * N;
    for (int i = lane; i < N; i += WAVE) {
        float e = __uint_as_float(keys[i]);
        float d = sqrtf(fmaxf(2.0f * e, 0.0f) + 1e-12f);
        dst[i] = (i < N - 1) ? d : 0.0f;
    }
}

__global__ __launch_bounds__(256) void diff_kernel(const float* __restrict__ ws,
                                                   float* __restrict__ out) {
    __shared__ float red[256];
    const int t = threadIdx.x;
    float sum = 0.0f;
    for (int idx = t; idx < 64 * N; idx += 256)
        sum += fabsf(ws[idx] - ws[64 * N + idx]);
    red[t] = sum;
    __syncthreads();
    for (int s = 128; s > 0; s >>= 1) {
        if (t < s) red[t] += red[t + s];
        __syncthreads();
    }
    if (t == 0) out[0] = red[0] * (1.0f / 64.0f);
}

extern "C" void kernel_launch(void* const* d_in, const int* in_sizes, int n_in,
                              void* d_out, int out_size, void* d_ws, size_t ws_size,
                              hipStream_t stream) {
    const float* gts = (const float*)d_in[0];
    const float* preds = (const float*)d_in[1];
    float* ws = (float*)d_ws;  // 2*64*1024*4 = 512 KiB
    hipLaunchKernelGGL(prim_kernel, dim3(128), dim3(WAVE), 0, stream, gts, preds, ws);
    hipLaunchKernelGGL(diff_kernel, dim3(1), dim3(256), 0, stream, ws, (float*)d_out);
}

// Round 3
// 601.223 us; speedup vs baseline: 1.8365x; 1.2724x over previous
//
#include <hip/hip_runtime.h>
#include <math.h>

#define N 1024
#define WAVE 64
#define QS 16   // slots per lane: N / WAVE

typedef float v2f __attribute__((ext_vector_type(2)));

__device__ __forceinline__ unsigned umin32(unsigned a, unsigned b) { return a < b ? a : b; }

// DPP row_shr min step (row = 16 lanes), identity = 0xFFFFFFFF
#define DPP_MIN_SHR(v, sh)                                                                   \
    do {                                                                                     \
        unsigned _t = (unsigned)__builtin_amdgcn_update_dpp(                                 \
            (int)0xFFFFFFFF, (int)(v), 0x110 | (sh), 0xF, 0xF, false);                       \
        (v) = umin32((v), _t);                                                               \
    } while (0)

// One wave per (input, batch). blk<64 -> gts, else preds.
__global__ __launch_bounds__(WAVE) void prim_kernel(const float* __restrict__ gts,
                                                    const float* __restrict__ preds,
                                                    float* __restrict__ ws) {
    __shared__ float4 pts[N];       // x, y, z, h = 0.5*|p|^2
    __shared__ unsigned keys[N];    // death keys (sortable uint = fp32 bits of e>=0, low4=slot)

    const int lane = threadIdx.x;
    const int blk = blockIdx.x;
    const int b = blk & 63;
    const float* __restrict__ src = (blk < 64 ? gts : preds) + (size_t)b * N * 3;

    // ---- stage points into LDS ----
    for (int k = lane; k < N; k += WAVE) {
        float x = src[3 * k], y = src[3 * k + 1], z = src[3 * k + 2];
        float h = 0.5f * (x * x + y * y + z * z);
        pts[k] = make_float4(x, y, z, h);
    }
    __syncthreads();

    // ---- register state: slot q owns point k = q*64 + lane; slots paired into v2f ----
    v2f pxv[QS / 2], pyv[QS / 2], pzv[QS / 2], phv[QS / 2];
    unsigned md[QS];   // min half-sq-dist key; >= 0x7F800000 means "in tree"
    #pragma unroll
    for (int i = 0; i < QS / 2; ++i) {
        float4 pa = pts[(2 * i) * WAVE + lane];
        float4 pb = pts[(2 * i + 1) * WAVE + lane];
        pxv[i] = (v2f){pa.x, pb.x};
        pyv[i] = (v2f){pa.y, pb.y};
        pzv[i] = (v2f){pa.z, pb.z};
        phv[i] = (v2f){pa.w, pb.w};
    }

    // ---- init: node 0 in tree, md = key(e(k,0)) ----
    {
        float4 p0 = pts[0];
        v2f jx = (v2f){-p0.x, -p0.x}, jy = (v2f){-p0.y, -p0.y};
        v2f jz = (v2f){-p0.z, -p0.z}, jw = (v2f){p0.w, p0.w};
        bool am0 = (lane == 0);
        phv[0].x = am0 ? INFINITY : phv[0].x;   // poison slot 0 of lane 0
        #pragma unroll
        for (int i = 0; i < QS / 2; ++i) {
            v2f t = phv[i] + jw;
            t = __builtin_elementwise_fma(pzv[i], jz, t);
            t = __builtin_elementwise_fma(pyv[i], jy, t);
            t = __builtin_elementwise_fma(pxv[i], jx, t);
            t = __builtin_elementwise_max(t, (v2f){0.0f, 0.0f});
            unsigned k0 = (__float_as_uint(t.x) & 0xFFFFFFF0u) | (unsigned)(2 * i);
            unsigned k1 = (__float_as_uint(t.y) & 0xFFFFFFF0u) | (unsigned)(2 * i + 1);
            md[2 * i] = k0;
            md[2 * i + 1] = k1;
        }
        md[0] = am0 ? 0xFFFFFFFFu : md[0];
    }

    // ---- Prim main loop: N-1 serial iterations ----
    #pragma unroll 2
    for (int it = 0; it < N - 1; ++it) {
        // local min: binary tree over 16 slots (depth 4)
        unsigned t0 = umin32(md[0], md[8]),  t1 = umin32(md[1], md[9]);
        unsigned t2 = umin32(md[2], md[10]), t3 = umin32(md[3], md[11]);
        unsigned t4 = umin32(md[4], md[12]), t5 = umin32(md[5], md[13]);
        unsigned t6 = umin32(md[6], md[14]), t7 = umin32(md[7], md[15]);
        t0 = umin32(t0, t4); t1 = umin32(t1, t5); t2 = umin32(t2, t6); t3 = umin32(t3, t7);
        t0 = umin32(t0, t2); t1 = umin32(t1, t3);
        unsigned lmin = umin32(t0, t1);

        // wave min: 4 DPP row_shr steps -> row mins at lanes 15/31/47/63
        unsigned v = lmin;
        DPP_MIN_SHR(v, 1);
        DPP_MIN_SHR(v, 2);
        DPP_MIN_SHR(v, 4);
        DPP_MIN_SHR(v, 8);
        unsigned r0 = (unsigned)__builtin_amdgcn_readlane((int)v, 15);
        unsigned r1 = (unsigned)__builtin_amdgcn_readlane((int)v, 31);
        unsigned r2 = (unsigned)__builtin_amdgcn_readlane((int)v, 47);
        unsigned r3 = (unsigned)__builtin_amdgcn_readlane((int)v, 63);
        unsigned gmin = umin32(umin32(r0, r1), umin32(r2, r3));

        // winning lane + slot
        unsigned long long mask = __ballot(lmin == gmin);
        int w = __ffsll((long long)mask) - 1;
        int qwin = (int)(gmin & 15u);
        int j = qwin * WAVE + w;

        if (lane == 0) keys[it] = gmin;

        // pre-step: poison new tree node (independent of pts[j] -> overlaps LDS wait)
        bool amw = (lane == w);
        #pragma unroll
        for (int q = 0; q < QS; ++q) {
            bool isj = amw && (q == qwin);
            md[q] = isj ? 0xFFFFFFFFu : md[q];
        }
        #pragma unroll
        for (int i = 0; i < QS / 2; ++i) {
            bool j0 = amw && (2 * i == qwin);
            bool j1 = amw && (2 * i + 1 == qwin);
            phv[i].x = j0 ? INFINITY : phv[i].x;   // future e = +INF exactly -> always-lose key
            phv[i].y = j1 ? INFINITY : phv[i].y;
        }

        // relax all owned slots against new node j (packed fp32)
        float4 pj = pts[j];   // broadcast ds_read_b128
        v2f jx = (v2f){-pj.x, -pj.x}, jy = (v2f){-pj.y, -pj.y};
        v2f jz = (v2f){-pj.z, -pj.z}, jw = (v2f){pj.w, pj.w};
        #pragma unroll
        for (int i = 0; i < QS / 2; ++i) {
            v2f t = phv[i] + jw;
            t = __builtin_elementwise_fma(pzv[i], jz, t);
            t = __builtin_elementwise_fma(pyv[i], jy, t);
            t = __builtin_elementwise_fma(pxv[i], jx, t);
            t = __builtin_elementwise_max(t, (v2f){0.0f, 0.0f});
            unsigned k0 = (__float_as_uint(t.x) & 0xFFFFFFF0u) | (unsigned)(2 * i);
            unsigned k1 = (__float_as_uint(t.y) & 0xFFFFFFF0u) | (unsigned)(2 * i + 1);
            md[2 * i] = umin32(md[2 * i], k0);
            md[2 * i + 1] = umin32(md[2 * i + 1], k1);
        }
    }

    if (lane == 0) keys[N - 1] = 0xFFFFFFFFu;   // pad: sorts to the end
    __syncthreads();

    // ---- bitonic sort of 1024 uint keys (ascending) ----
    for (int k = 2; k <= N; k <<= 1) {
        for (int j = k >> 1; j > 0; j >>= 1) {
            for (int base = 0; base < N; base += WAVE) {
                int i = base + lane;
                int ixj = i ^ j;
                if (ixj > i) {
                    unsigned a = keys[i], c = keys[ixj];
                    bool up = ((i & k) == 0);
                    if ((a > c) == up) { keys[i] = c; keys[ixj] = a; }
                }
            }
            __syncthreads();
        }
    }

    // ---- convert keys -> deaths, write sorted; pad slot -> 0 ----
    float* dst = ws + (size_t)blk * N;
    for (int i = lane; i < N; i += WAVE) {
        float e = __uint_as_float(keys[i]);
        float d = sqrtf(fmaxf(2.0f * e, 0.0f) + 1e-12f);
        dst[i] = (i < N - 1) ? d : 0.0f;
    }
}

__global__ __launch_bounds__(256) void diff_kernel(const float* __restrict__ ws,
                                                   float* __restrict__ out) {
    __shared__ float red[256];
    const int t = threadIdx.x;
    float sum = 0.0f;
    for (int idx = t; idx < 64 * N; idx += 256)
        sum += fabsf(ws[idx] - ws[64 * N + idx]);
    red[t] = sum;
    __syncthreads();
    for (int s = 128; s > 0; s >>= 1) {
        if (t < s) red[t] += red[t + s];
        __syncthreads();
    }
    if (t == 0) out[0] = red[0] * (1.0f / 64.0f);
}

extern "C" void kernel_launch(void* const* d_in, const int* in_sizes, int n_in,
                              void* d_out, int out_size, void* d_ws, size_t ws_size,
                              hipStream_t stream) {
    const float* gts = (const float*)d_in[0];
    const float* preds = (const float*)d_in[1];
    float* ws = (float*)d_ws;  // 2*64*1024*4 = 512 KiB
    hipLaunchKernelGGL(prim_kernel, dim3(128), dim3(WAVE), 0, stream, gts, preds, ws);
    hipLaunchKernelGGL(diff_kernel, dim3(1), dim3(256), 0, stream, ws, (float*)d_out);
}

// Round 5
// 502.199 us; speedup vs baseline: 2.1986x; 1.1972x over previous
//
#include <hip/hip_runtime.h>
#include <math.h>

#define N 1024
#define T 512            // threads per block = 8 waves
#define PHASE_CAP 24

typedef float v2f __attribute__((ext_vector_type(2)));
typedef unsigned long long ull;

#define INF64 0xFFFFFFFFFFFFFFFFull
#define INF32 0xFFFFFFFFu

__device__ __forceinline__ unsigned umin32(unsigned a, unsigned b) { return a < b ? a : b; }
__device__ __forceinline__ unsigned umax32(unsigned a, unsigned b) { return a > b ? a : b; }

// One block per (input, batch): blk<64 -> gts, else preds. Boruvka MST -> sorted deaths.
// Edge order: canonical key (e_trunc, min_id, max_id) -- globally distinct, so hook
// graph cycles are exactly mutual 2-cycles sharing one undirected edge.
__global__ __launch_bounds__(T) void boruvka_kernel(const float* __restrict__ gts,
                                                    const float* __restrict__ preds,
                                                    float* __restrict__ ws) {
    __shared__ float4 pts[N];        // x, y, z, h = 0.5*|p|^2
    __shared__ unsigned comp[N];     // component label (always a current root id)
    __shared__ ull bestComp[N];      // per-root canonical best: (e_trunc<<20)|(mn<<10)|mx
    __shared__ unsigned parent[N];
    __shared__ float deaths[N];
    __shared__ int deathCount;

    const int t = threadIdx.x;
    const int blk = blockIdx.x;
    const int b = blk & 63;
    const float* __restrict__ src = (blk < 64 ? gts : preds) + (size_t)b * N * 3;

    // ---- stage + init ----
    for (int k = t; k < N; k += T) {
        float x = src[3 * k], y = src[3 * k + 1], z = src[3 * k + 2];
        pts[k] = make_float4(x, y, z, 0.5f * (x * x + y * y + z * z));
        comp[k] = k;
        parent[k] = k;
        deaths[k] = 0.0f;
        bestComp[k] = INF64;
    }
    if (t == 0) deathCount = 0;
    __syncthreads();

    // owned nodes: i0 = t, i1 = t + T; coords packed (node0, node1)
    const int i0 = t, i1 = t + T;
    float4 p0 = pts[i0], p1 = pts[i1];
    const v2f phx = (v2f){p0.x, p1.x};
    const v2f phy = (v2f){p0.y, p1.y};
    const v2f phz = (v2f){p0.z, p1.z};
    const v2f phh = (v2f){p0.w, p1.w};

    for (int phase = 0; phase < PHASE_CAP; ++phase) {
        const unsigned c0 = comp[i0], c1 = comp[i1];

        // ---- scan: per-node min cross-comp edge; key32 = (e&~0x7FF) | j ----
        // For fixed node i, min-by-j at equal e_trunc == canonical (mn,mx) order.
        unsigned best0 = INF32, best1 = INF32;
        #pragma unroll 4
        for (int j = 0; j < N; ++j) {
            float4 pj = pts[j];          // uniform addr -> LDS broadcast
            unsigned cj = comp[j];
            v2f e = phh + (v2f){pj.w, pj.w};
            e = __builtin_elementwise_fma(phx, (v2f){-pj.x, -pj.x}, e);
            e = __builtin_elementwise_fma(phy, (v2f){-pj.y, -pj.y}, e);
            e = __builtin_elementwise_fma(phz, (v2f){-pj.z, -pj.z}, e);
            e = __builtin_elementwise_max(e, (v2f){0.0f, 0.0f});
            unsigned k0 = (__float_as_uint(e.x) & 0xFFFFF800u) | (unsigned)j;
            unsigned k1 = (__float_as_uint(e.y) & 0xFFFFF800u) | (unsigned)j;
            k0 = (cj == c0) ? INF32 : k0;   // suppress same-component (incl. j==i)
            k1 = (cj == c1) ? INF32 : k1;
            best0 = umin32(best0, k0);
            best1 = umin32(best1, k1);
        }
        // comp-level canonical u64 atomicMin
        if (best0 != INF32) {
            unsigned j0 = best0 & 0x3FFu, e0 = best0 & 0xFFFFF800u;
            unsigned mn = umin32((unsigned)i0, j0), mx = umax32((unsigned)i0, j0);
            atomicMin(&bestComp[c0], ((ull)e0 << 20) | (ull)((mn << 10) | mx));
        }
        if (best1 != INF32) {
            unsigned j1 = best1 & 0x3FFu, e1 = best1 & 0xFFFFF800u;
            unsigned mn = umin32((unsigned)i1, j1), mx = umax32((unsigned)i1, j1);
            atomicMin(&bestComp[c1], ((ull)e1 << 20) | (ull)((mn << 10) | mx));
        }
        __syncthreads();

        // ---- hook: roots only, own-label write only ----
        bool isRoot[2];
        #pragma unroll
        for (int s = 0; s < 2; ++s) {
            int c = t + s * T;
            bool r = (parent[c] == (unsigned)c);
            isRoot[s] = r;
            ull bc = bestComp[c];
            if (r && bc != INF64) {
                unsigned mn = (unsigned)((bc >> 10) & 0x3FFu);
                unsigned mx = (unsigned)(bc & 0x3FFu);
                unsigned cm = comp[mn];
                unsigned far = (cm == (unsigned)c) ? comp[mx] : cm;
                parent[c] = far;
            }
        }
        __syncthreads();

        // ---- resolve: READ-ONLY pass; only roots that hooked THIS phase ----
        bool win0 = false, win1 = false;
        #pragma unroll
        for (int s = 0; s < 2; ++s) {
            int c = t + s * T;
            unsigned p = parent[c];
            if ((s == 0 ? isRoot[0] : isRoot[1]) && p != (unsigned)c) {
                unsigned gp = parent[p];
                bool mutual = (gp == (unsigned)c);   // distinct keys => same undirected edge
                bool rec = !mutual || ((unsigned)c < p);
                bool w = mutual && ((unsigned)c < p);
                if (s == 0) win0 = w; else win1 = w;
                if (rec) {
                    unsigned e_bits = (unsigned)(bestComp[c] >> 20);
                    int idx = atomicAdd(&deathCount, 1);
                    if (idx < N - 1) {
                        float e = __uint_as_float(e_bits);
                        deaths[idx] = sqrtf(fmaxf(2.0f * e, 0.0f) + 1e-12f);
                    }
                }
            }
        }
        __syncthreads();

        // ---- commit mutual winners as merged roots ----
        if (win0) parent[i0] = (unsigned)i0;
        if (win1) parent[i1] = (unsigned)i1;
        __syncthreads();

        // ---- pointer jumping (2^10 covers chains <= 1024) ----
        for (int r = 0; r < 10; ++r) {
            unsigned a = parent[t], bb = parent[t + T];
            unsigned na = parent[a], nb = parent[bb];
            __syncthreads();
            parent[t] = na;
            parent[t + T] = nb;
            __syncthreads();
        }

        // ---- relabel + reset ----
        comp[i0] = parent[comp[i0]];
        comp[i1] = parent[comp[i1]];
        bestComp[t] = INF64;
        bestComp[t + T] = INF64;
        __syncthreads();

        if (deathCount >= N - 1) break;
    }

    // ---- sort 1024 floats (1023 deaths + INF pad) ascending, bitonic ----
    if (t == 0) deaths[N - 1] = INFINITY;
    __syncthreads();
    for (int k = 2; k <= N; k <<= 1) {
        for (int j = k >> 1; j > 0; j >>= 1) {
            for (int i = t; i < N; i += T) {
                int ixj = i ^ j;
                if (ixj > i) {
                    float a = deaths[i], c = deaths[ixj];
                    bool up = ((i & k) == 0);
                    if ((a > c) == up) { deaths[i] = c; deaths[ixj] = a; }
                }
            }
            __syncthreads();
        }
    }

    // ---- write sorted deaths; pad slot -> 0 ----
    float* dst = ws + (size_t)blk * N;
    for (int i = t; i < N; i += T)
        dst[i] = (i < N - 1) ? deaths[i] : 0.0f;
}

__global__ __launch_bounds__(256) void diff_kernel(const float* __restrict__ ws,
                                                   float* __restrict__ out) {
    __shared__ float red[256];
    const int t = threadIdx.x;
    float sum = 0.0f;
    for (int idx = t; idx < 64 * N; idx += 256)
        sum += fabsf(ws[idx] - ws[64 * N + idx]);
    red[t] = sum;
    __syncthreads();
    for (int s = 128; s > 0; s >>= 1) {
        if (t < s) red[t] += red[t + s];
        __syncthreads();
    }
    if (t == 0) out[0] = red[0] * (1.0f / 64.0f);
}

extern "C" void kernel_launch(void* const* d_in, const int* in_sizes, int n_in,
                              void* d_out, int out_size, void* d_ws, size_t ws_size,
                              hipStream_t stream) {
    const float* gts = (const float*)d_in[0];
    const float* preds = (const float*)d_in[1];
    float* ws = (float*)d_ws;  // 2*64*1024*4 = 512 KiB
    hipLaunchKernelGGL(boruvka_kernel, dim3(128), dim3(T), 0, stream, gts, preds, ws);
    hipLaunchKernelGGL(diff_kernel, dim3(1), dim3(256), 0, stream, ws, (float*)d_out);
}

// Round 6
// 401.920 us; speedup vs baseline: 2.7472x; 1.2495x over previous
//
#include <hip/hip_runtime.h>
#include <math.h>

#define N 1024
#define T 1024           // 16 waves: 4 per SIMD
#define HALF 512
#define PHASE_CAP 24

typedef float v2f __attribute__((ext_vector_type(2)));
typedef unsigned long long ull;

#define INF64 0xFFFFFFFFFFFFFFFFull
#define INF32 0xFFFFFFFFu

__device__ __forceinline__ unsigned umin32(unsigned a, unsigned b) { return a < b ? a : b; }
__device__ __forceinline__ unsigned umax32(unsigned a, unsigned b) { return a > b ? a : b; }

// One block per (input, batch): blk<64 -> gts, else preds. Boruvka MST -> sorted deaths.
// comp bits live in pts[j].w so the scan does ONE ds_read_b128 per j.
// Thread t owns nodes (n, n+512), n = t&511, and scans j-half h = t>>9.
__global__ __launch_bounds__(T) void boruvka_kernel(const float* __restrict__ gts,
                                                    const float* __restrict__ preds,
                                                    float* __restrict__ ws) {
    __shared__ float4 pts[N];        // x, y, z, w = comp bits (refreshed per phase)
    __shared__ unsigned comp[N];
    __shared__ ull bestComp[N];      // canonical best per root: (e_trunc<<20)|(mn<<10)|mx
    __shared__ unsigned parent[N];
    __shared__ unsigned pb[2][N];    // per-half per-node partial best
    __shared__ float deaths[N];
    __shared__ int deathCount;

    const int t = threadIdx.x;
    const int blk = blockIdx.x;
    const int b = blk & 63;
    const float* __restrict__ src = (blk < 64 ? gts : preds) + (size_t)b * N * 3;

    // ---- stage + init (thread t owns point t for staging) ----
    {
        float x = src[3 * t], y = src[3 * t + 1], z = src[3 * t + 2];
        pts[t] = make_float4(x, y, z, __uint_as_float((unsigned)t));
        comp[t] = (unsigned)t;
        parent[t] = (unsigned)t;
        deaths[t] = 0.0f;
        bestComp[t] = INF64;
    }
    if (t == 0) deathCount = 0;
    __syncthreads();

    const int n = t & (HALF - 1);
    const int h = t >> 9;
    const int n2 = n + HALF;
    const int jbase = h * HALF;
    float4 pA = pts[n], pB = pts[n2];
    const v2f pxv = (v2f){pA.x, pB.x};
    const v2f pyv = (v2f){pA.y, pB.y};
    const v2f pzv = (v2f){pA.z, pB.z};

    for (int phase = 0; phase < PHASE_CAP; ++phase) {
        const unsigned c0 = comp[n], c1 = comp[n2];

        // ---- scan: half j-range, 2 nodes packed; key32 = (e&~0x7FF)|j ----
        unsigned best0 = INF32, best1 = INF32;
        #pragma unroll 8
        for (int jj = 0; jj < HALF; ++jj) {
            int j = jbase + jj;
            float4 pj = pts[j];              // uniform addr -> LDS broadcast (b128)
            unsigned cj = __float_as_uint(pj.w);
            v2f dx = pxv - (v2f){pj.x, pj.x};
            v2f dy = pyv - (v2f){pj.y, pj.y};
            v2f dz = pzv - (v2f){pj.z, pj.z};
            v2f e = dx * dx;
            e = __builtin_elementwise_fma(dy, dy, e);
            e = __builtin_elementwise_fma(dz, dz, e);
            unsigned k0 = (__float_as_uint(e.x) & 0xFFFFF800u) | (unsigned)j;
            unsigned k1 = (__float_as_uint(e.y) & 0xFFFFF800u) | (unsigned)j;
            k0 = (cj == c0) ? INF32 : k0;    // suppress same-component (incl. j==self)
            k1 = (cj == c1) ? INF32 : k1;
            best0 = umin32(best0, k0);
            best1 = umin32(best1, k1);
        }
        pb[h][n] = best0;
        pb[h][n2] = best1;
        __syncthreads();

        // ---- combine halves + per-component canonical atomicMin (h==0 threads) ----
        if (h == 0) {
            #pragma unroll
            for (int s = 0; s < 2; ++s) {
                int m = s == 0 ? n : n2;
                unsigned fb = umin32(pb[0][m], pb[1][m]);
                if (fb != INF32) {
                    unsigned j = fb & 0x3FFu, e = fb & 0xFFFFF800u;
                    unsigned mn = umin32((unsigned)m, j), mx = umax32((unsigned)m, j);
                    atomicMin(&bestComp[comp[m]], ((ull)e << 20) | (ull)((mn << 10) | mx));
                }
            }
        }
        __syncthreads();

        // ---- hook: component c = t; roots only, own-label write ----
        const unsigned c = (unsigned)t;
        const bool isRoot = (parent[c] == c);
        {
            ull bc = bestComp[c];
            if (isRoot && bc != INF64) {
                unsigned mn = (unsigned)((bc >> 10) & 0x3FFu);
                unsigned mx = (unsigned)(bc & 0x3FFu);
                unsigned cm = comp[mn];
                parent[c] = (cm == c) ? comp[mx] : cm;
            }
        }
        __syncthreads();

        // ---- resolve (read-only): only roots that hooked this phase ----
        bool win = false;
        {
            unsigned p = parent[c];
            if (isRoot && p != c) {
                unsigned gp = parent[p];
                bool mutual = (gp == c);          // distinct keys => same undirected edge
                bool rec = !mutual || (c < p);
                win = mutual && (c < p);
                if (rec) {
                    unsigned e_bits = (unsigned)(bestComp[c] >> 20);
                    int idx = atomicAdd(&deathCount, 1);
                    if (idx < N - 1)
                        deaths[idx] = sqrtf(__uint_as_float(e_bits) + 1e-12f);
                }
            }
        }
        __syncthreads();

        // ---- commit mutual winners as merged roots ----
        if (win) parent[c] = c;
        __syncthreads();

        // ---- pointer jumping (2^10 covers chains <= 1024) ----
        for (int r = 0; r < 10; ++r) {
            unsigned a = parent[t];
            unsigned na = parent[a];
            __syncthreads();
            parent[t] = na;
            __syncthreads();
        }

        // ---- relabel + refresh comp-in-w + reset ----
        unsigned nc = parent[comp[t]];
        comp[t] = nc;
        pts[t].w = __uint_as_float(nc);
        bestComp[t] = INF64;
        __syncthreads();

        if (deathCount >= N - 1) break;
    }

    // ---- bitonic sort 1024 floats (1023 deaths + INF pad) ascending ----
    if (t == 0) deaths[N - 1] = INFINITY;
    __syncthreads();
    for (int k = 2; k <= N; k <<= 1) {
        for (int j = k >> 1; j > 0; j >>= 1) {
            int ixj = t ^ j;
            if (ixj > t) {
                float a = deaths[t], cc = deaths[ixj];
                bool up = ((t & k) == 0);
                if ((a > cc) == up) { deaths[t] = cc; deaths[ixj] = a; }
            }
            __syncthreads();
        }
    }

    // ---- write sorted deaths; pad slot -> 0 ----
    float* dst = ws + (size_t)blk * N;
    dst[t] = (t < N - 1) ? deaths[t] : 0.0f;
}

// 64 blocks: per-batch partial sums of |deaths_a - deaths_b|
__global__ __launch_bounds__(256) void diff_partial(const float* __restrict__ ws,
                                                    float* __restrict__ partial) {
    __shared__ float red[256];
    const int t = threadIdx.x;
    const int b = blockIdx.x;
    const float* a = ws + (size_t)b * N;
    const float* c = ws + (size_t)(64 + b) * N;
    float sum = 0.0f;
    for (int i = t; i < N; i += 256)
        sum += fabsf(a[i] - c[i]);
    red[t] = sum;
    __syncthreads();
    for (int s = 128; s > 0; s >>= 1) {
        if (t < s) red[t] += red[t + s];
        __syncthreads();
    }
    if (t == 0) partial[b] = red[0];
}

__global__ __launch_bounds__(64) void diff_final(const float* __restrict__ partial,
                                                 float* __restrict__ out) {
    const int t = threadIdx.x;
    float v = partial[t];
    #pragma unroll
    for (int off = 32; off > 0; off >>= 1)
        v += __shfl_down(v, off, 64);
    if (t == 0) out[0] = v * (1.0f / 64.0f);
}

extern "C" void kernel_launch(void* const* d_in, const int* in_sizes, int n_in,
                              void* d_out, int out_size, void* d_ws, size_t ws_size,
                              hipStream_t stream) {
    const float* gts = (const float*)d_in[0];
    const float* preds = (const float*)d_in[1];
    float* ws = (float*)d_ws;                    // 128*1024 floats = 512 KiB
    float* partial = ws + 128 * N;               // + 64 floats
    hipLaunchKernelGGL(boruvka_kernel, dim3(128), dim3(T), 0, stream, gts, preds, ws);
    hipLaunchKernelGGL(diff_partial, dim3(64), dim3(256), 0, stream, ws, partial);
    hipLaunchKernelGGL(diff_final, dim3(1), dim3(64), 0, stream, partial, (float*)d_out);
}

// Round 7
// 341.361 us; speedup vs baseline: 3.2345x; 1.1774x over previous
//
#include <hip/hip_runtime.h>
#include <math.h>

#define N 1024
#define T 1024           // 16 waves: 4 per SIMD
#define HALF 512
#define PHASE_CAP 10     // comps at least halve per phase; <=4 phases reach <=64

typedef float v2f __attribute__((ext_vector_type(2)));
typedef unsigned long long ull;

#define INF64 0xFFFFFFFFFFFFFFFFull
#define INF32 0xFFFFFFFFu

__device__ __forceinline__ unsigned umin32(unsigned a, unsigned b) { return a < b ? a : b; }
__device__ __forceinline__ unsigned umax32(unsigned a, unsigned b) { return a > b ? a : b; }

// DPP row_shr min step (row = 16 lanes), identity = 0xFFFFFFFF
#define DPP_MIN_SHR(v, sh)                                                                   \
    do {                                                                                     \
        unsigned _t = (unsigned)__builtin_amdgcn_update_dpp(                                 \
            (int)0xFFFFFFFF, (int)(v), 0x110 | (sh), 0xF, 0xF, false);                       \
        (v) = umin32((v), _t);                                                               \
    } while (0)

// One block per (input, batch). Boruvka phases until <=64 comps, then contracted Prim.
__global__ __launch_bounds__(T) void boruvka_kernel(const float* __restrict__ gts,
                                                    const float* __restrict__ preds,
                                                    float* __restrict__ ws) {
    __shared__ float4 pts[N];        // x, y, z, w = comp bits (refreshed per phase)
    __shared__ float4 spts[N];       // comp-sorted points (Prim stage)
    __shared__ unsigned comp[N];
    __shared__ ull bestComp[N];      // phases: canonical best per root; Prim: seg offsets
    __shared__ unsigned parent[N];
    __shared__ unsigned pb[2][N];    // phases: per-half partials; Prim: sort keys + wavemins
    __shared__ float deaths[N];
    __shared__ int deathCount;

    const int t = threadIdx.x;
    const int blk = blockIdx.x;
    const int b = blk & 63;
    const float* __restrict__ src = (blk < 64 ? gts : preds) + (size_t)b * N * 3;

    // ---- stage + init ----
    {
        float x = src[3 * t], y = src[3 * t + 1], z = src[3 * t + 2];
        pts[t] = make_float4(x, y, z, __uint_as_float((unsigned)t));
        comp[t] = (unsigned)t;
        parent[t] = (unsigned)t;
        deaths[t] = 0.0f;
        bestComp[t] = INF64;
    }
    if (t == 0) deathCount = 0;
    __syncthreads();

    const int n = t & (HALF - 1);
    const int h = t >> 9;
    const int n2 = n + HALF;
    const int jbase = h * HALF;
    float4 pA = pts[n], pB = pts[n2];
    const v2f pxv = (v2f){pA.x, pB.x};
    const v2f pyv = (v2f){pA.y, pB.y};
    const v2f pzv = (v2f){pA.z, pB.z};

    // ================= Boruvka phases =================
    for (int phase = 0; phase < PHASE_CAP; ++phase) {
        const unsigned c0 = comp[n], c1 = comp[n2];

        unsigned best0 = INF32, best1 = INF32;
        #pragma unroll 8
        for (int jj = 0; jj < HALF; ++jj) {
            int j = jbase + jj;
            float4 pj = pts[j];              // uniform addr -> LDS broadcast
            unsigned cj = __float_as_uint(pj.w);
            v2f dx = pxv - (v2f){pj.x, pj.x};
            v2f dy = pyv - (v2f){pj.y, pj.y};
            v2f dz = pzv - (v2f){pj.z, pj.z};
            v2f e = dx * dx;
            e = __builtin_elementwise_fma(dy, dy, e);
            e = __builtin_elementwise_fma(dz, dz, e);
            unsigned k0 = (__float_as_uint(e.x) & 0xFFFFF800u) | (unsigned)j;
            unsigned k1 = (__float_as_uint(e.y) & 0xFFFFF800u) | (unsigned)j;
            k0 = (cj == c0) ? INF32 : k0;
            k1 = (cj == c1) ? INF32 : k1;
            best0 = umin32(best0, k0);
            best1 = umin32(best1, k1);
        }
        pb[h][n] = best0;
        pb[h][n2] = best1;
        __syncthreads();

        if (h == 0) {
            #pragma unroll
            for (int s = 0; s < 2; ++s) {
                int m = s == 0 ? n : n2;
                unsigned fb = umin32(pb[0][m], pb[1][m]);
                if (fb != INF32) {
                    unsigned j = fb & 0x3FFu, e = fb & 0xFFFFF800u;
                    unsigned mn = umin32((unsigned)m, j), mx = umax32((unsigned)m, j);
                    atomicMin(&bestComp[comp[m]], ((ull)e << 20) | (ull)((mn << 10) | mx));
                }
            }
        }
        __syncthreads();

        const unsigned c = (unsigned)t;
        const bool isRoot = (parent[c] == c);
        {
            ull bc = bestComp[c];
            if (isRoot && bc != INF64) {
                unsigned mn = (unsigned)((bc >> 10) & 0x3FFu);
                unsigned mx = (unsigned)(bc & 0x3FFu);
                unsigned cm = comp[mn];
                parent[c] = (cm == c) ? comp[mx] : cm;
            }
        }
        __syncthreads();

        bool win = false;
        {
            unsigned p = parent[c];
            if (isRoot && p != c) {
                unsigned gp = parent[p];
                bool mutual = (gp == c);
                bool rec = !mutual || (c < p);
                win = mutual && (c < p);
                if (rec) {
                    unsigned e_bits = (unsigned)(bestComp[c] >> 20);
                    int idx = atomicAdd(&deathCount, 1);
                    if (idx < N - 1)
                        deaths[idx] = sqrtf(__uint_as_float(e_bits) + 1e-12f);
                }
            }
        }
        __syncthreads();

        if (win) parent[c] = c;
        __syncthreads();

        for (int r = 0; r < 10; ++r) {
            unsigned a = parent[t];
            unsigned na = parent[a];
            __syncthreads();
            parent[t] = na;
            __syncthreads();
        }

        unsigned nc = parent[comp[t]];
        comp[t] = nc;
        pts[t].w = __uint_as_float(nc);
        bestComp[t] = INF64;
        __syncthreads();

        if (N - deathCount <= 64) break;
    }

    // ================= Contracted Prim on remaining comps =================
    const int dcbase = deathCount;       // uniform (post-barrier)
    const int comps = N - dcbase;
    if (comps > 1) {
        // sort keys (comp<<10 | node) ascending -> group nodes by component
        unsigned* sk = &pb[0][0];
        unsigned* wavemin = &pb[1][0];
        unsigned* segbeg = (unsigned*)&bestComp[0];
        unsigned* segend = segbeg + N;
        sk[t] = (comp[t] << 10) | (unsigned)t;
        __syncthreads();
        for (int k = 2; k <= N; k <<= 1) {
            for (int j = k >> 1; j > 0; j >>= 1) {
                int ixj = t ^ j;
                if (ixj > t) {
                    unsigned a = sk[t], cc = sk[ixj];
                    bool up = ((t & k) == 0);
                    if ((a > cc) == up) { sk[t] = cc; sk[ixj] = a; }
                }
                __syncthreads();
            }
        }
        {
            unsigned key = sk[t];
            unsigned cme = key >> 10;
            spts[t] = pts[key & 0x3FFu];
            if (t == 0 || (sk[t - 1] >> 10) != cme) segbeg[cme] = (unsigned)t;
            if (t == N - 1 || (sk[t + 1] >> 10) != cme) segend[cme] = (unsigned)t + 1;
        }
        __syncthreads();

        // per-thread node t state
        float4 pme = pts[t];
        float px = pme.x, py = pme.y, pz = pme.z;
        const unsigned myc = comp[t];
        unsigned md = INF32;                 // key = (e & ~0x3FF) | node
        unsigned c_cur = comp[0];            // start component (uniform)
        if (myc == c_cur) px = INFINITY;     // in-tree poison: e -> INF keys (always lose)

        const int lane = t & 63;
        const int wid = t >> 6;

        for (int step = 0; step < comps - 1; ++step) {
            // relax own node vs members of newly added component (wave-uniform range)
            int jb = (int)segbeg[c_cur], je = (int)segend[c_cur];
            for (int jj = jb; jj < je; ++jj) {
                float4 p = spts[jj];         // uniform addr -> broadcast
                float dx = px - p.x, dy = py - p.y, dz = pz - p.z;
                float e = dx * dx;
                e = fmaf(dy, dy, e);
                e = fmaf(dz, dz, e);
                unsigned key = (__float_as_uint(e) & 0xFFFFFC00u) | (unsigned)t;
                md = umin32(md, key);
            }
            // wave min via DPP, then 16-wave combine in LDS
            unsigned v = md;
            DPP_MIN_SHR(v, 1);
            DPP_MIN_SHR(v, 2);
            DPP_MIN_SHR(v, 4);
            DPP_MIN_SHR(v, 8);
            unsigned r0 = (unsigned)__builtin_amdgcn_readlane((int)v, 15);
            unsigned r1 = (unsigned)__builtin_amdgcn_readlane((int)v, 31);
            unsigned r2 = (unsigned)__builtin_amdgcn_readlane((int)v, 47);
            unsigned r3 = (unsigned)__builtin_amdgcn_readlane((int)v, 63);
            if (lane == 0) wavemin[wid] = umin32(umin32(r0, r1), umin32(r2, r3));
            __syncthreads();
            unsigned G = wavemin[0];
            #pragma unroll
            for (int k = 1; k < 16; ++k) G = umin32(G, wavemin[k]);
            unsigned winner = G & 0x3FFu;
            c_cur = comp[winner];            // uniform
            if (t == 0)
                deaths[dcbase + step] = sqrtf(__uint_as_float(G & 0xFFFFFC00u) + 1e-12f);
            if (myc == c_cur) { px = INFINITY; md = INF32; }   // whole comp joins tree
            __syncthreads();                 // wavemin consumed before next overwrite
        }
    }

    // ---- bitonic sort 1024 floats (1023 deaths + INF pad) ascending ----
    if (t == 0) deaths[N - 1] = INFINITY;
    __syncthreads();
    for (int k = 2; k <= N; k <<= 1) {
        for (int j = k >> 1; j > 0; j >>= 1) {
            int ixj = t ^ j;
            if (ixj > t) {
                float a = deaths[t], cc = deaths[ixj];
                bool up = ((t & k) == 0);
                if ((a > cc) == up) { deaths[t] = cc; deaths[ixj] = a; }
            }
            __syncthreads();
        }
    }

    float* dst = ws + (size_t)blk * N;
    dst[t] = (t < N - 1) ? deaths[t] : 0.0f;
}

// 64 blocks: per-batch partial sums of |deaths_a - deaths_b|
__global__ __launch_bounds__(256) void diff_partial(const float* __restrict__ ws,
                                                    float* __restrict__ partial) {
    __shared__ float red[256];
    const int t = threadIdx.x;
    const int b = blockIdx.x;
    const float* a = ws + (size_t)b * N;
    const float* c = ws + (size_t)(64 + b) * N;
    float sum = 0.0f;
    for (int i = t; i < N; i += 256)
        sum += fabsf(a[i] - c[i]);
    red[t] = sum;
    __syncthreads();
    for (int s = 128; s > 0; s >>= 1) {
        if (t < s) red[t] += red[t + s];
        __syncthreads();
    }
    if (t == 0) partial[b] = red[0];
}

__global__ __launch_bounds__(64) void diff_final(const float* __restrict__ partial,
                                                 float* __restrict__ out) {
    const int t = threadIdx.x;
    float v = partial[t];
    #pragma unroll
    for (int off = 32; off > 0; off >>= 1)
        v += __shfl_down(v, off, 64);
    if (t == 0) out[0] = v * (1.0f / 64.0f);
}

extern "C" void kernel_launch(void* const* d_in, const int* in_sizes, int n_in,
                              void* d_out, int out_size, void* d_ws, size_t ws_size,
                              hipStream_t stream) {
    const float* gts = (const float*)d_in[0];
    const float* preds = (const float*)d_in[1];
    float* ws = (float*)d_ws;                    // 128*1024 floats = 512 KiB
    float* partial = ws + 128 * N;               // + 64 floats
    hipLaunchKernelGGL(boruvka_kernel, dim3(128), dim3(T), 0, stream, gts, preds, ws);
    hipLaunchKernelGGL(diff_partial, dim3(64), dim3(256), 0, stream, ws, partial);
    hipLaunchKernelGGL(diff_final, dim3(1), dim3(64), 0, stream, partial, (float*)d_out);
}